// Round 1
// baseline (2069.155 us; speedup 1.0000x reference)
//
#include <hip/hip_runtime.h>
#include <stdint.h>

#define NNODES 50000
#define NEDGES 800000
#define ND 64
#define ED 16
#define H 128
#define KE 144   // 2*ND + ED
#define KN 192   // ND + H
#define BN_EPS 1e-5f

__device__ __forceinline__ float bf2f(unsigned short u) {
    unsigned int v = ((unsigned int)u) << 16;
    return __uint_as_float(v);
}
__device__ __forceinline__ unsigned short f2bf(float f) {
    unsigned int x = __float_as_uint(f);
    unsigned int r = (x + 0x7FFFu + ((x >> 16) & 1u)) >> 16;
    return (unsigned short)r;
}

// ---- fold We2@Wm into one 128x128 matrix, b2m = be2@Wm + bm ----
__global__ void k_fold(const float* __restrict__ We2, const float* __restrict__ be2,
                       const float* __restrict__ Wm, const float* __restrict__ bm,
                       float* __restrict__ W2m, float* __restrict__ b2m) {
    int j = threadIdx.x;
    int i = blockIdx.x;
    if (i < H) {
        float acc = 0.f;
        for (int k = 0; k < H; ++k) acc = fmaf(We2[i * H + k], Wm[k * H + j], acc);
        W2m[i * H + j] = acc;
    } else {
        float acc = bm[j];
        for (int k = 0; k < H; ++k) acc = fmaf(be2[k], Wm[k * H + j], acc);
        b2m[j] = acc;
    }
}

// ---- edge pass 1: h1 = [x[row],x[col],ea] @ We1 + be1 ; store bf16 ; accumulate BN stats ----
__launch_bounds__(256)
__global__ void k_edge1(const float* __restrict__ x, const int* __restrict__ ei,
                        const float* __restrict__ ea, const float* __restrict__ We1,
                        const float* __restrict__ be1, unsigned short* __restrict__ h1,
                        float* __restrict__ gS, float* __restrict__ gSS) {
    __shared__ float sIn[KE][68];      // transposed edge-input tile, 64 edges, pad 68
    __shared__ float sS[H], sSS[H];
    const int tid = threadIdx.x;
    const int e0 = blockIdx.x * 64;
    if (tid < H) { sS[tid] = 0.f; sSS[tid] = 0.f; }
    {
        const int le = tid >> 2, q = tid & 3;
        const int e = e0 + le;
        const int row = ei[e], col = ei[NEDGES + e];
        const float4* x4 = (const float4*)x;
        const float4* ea4 = (const float4*)ea;
        for (int t = q; t < 36; t += 4) {
            float4 v;
            if (t < 16)      v = x4[row * 16 + t];
            else if (t < 32) v = x4[col * 16 + (t - 16)];
            else             v = ea4[e * 4 + (t - 32)];
            int k0 = 4 * t;
            sIn[k0 + 0][le] = v.x; sIn[k0 + 1][le] = v.y;
            sIn[k0 + 2][le] = v.z; sIn[k0 + 3][le] = v.w;
        }
    }
    __syncthreads();
    const int f4 = tid & 31;   // features j0 = 4*f4 .. +3
    const int eg = tid >> 5;   // edges eg*8 .. +7
    float acc[4][8];
    #pragma unroll
    for (int a = 0; a < 4; ++a)
        #pragma unroll
        for (int b = 0; b < 8; ++b) acc[a][b] = 0.f;
    const float4* W4 = (const float4*)We1;
    #pragma unroll 4
    for (int k = 0; k < KE; ++k) {
        float4 w = W4[k * 32 + f4];
        float4 a0 = *(const float4*)&sIn[k][eg * 8];
        float4 a1 = *(const float4*)&sIn[k][eg * 8 + 4];
        float av[8] = {a0.x, a0.y, a0.z, a0.w, a1.x, a1.y, a1.z, a1.w};
        float wv[4] = {w.x, w.y, w.z, w.w};
        #pragma unroll
        for (int a = 0; a < 4; ++a)
            #pragma unroll
            for (int b = 0; b < 8; ++b) acc[a][b] = fmaf(wv[a], av[b], acc[a][b]);
    }
    const int j0 = 4 * f4;
    #pragma unroll
    for (int a = 0; a < 4; ++a) {
        float bia = be1[j0 + a];
        float s = 0.f, ss = 0.f;
        #pragma unroll
        for (int b = 0; b < 8; ++b) {
            float v = acc[a][b] + bia;
            acc[a][b] = v;
            s += v; ss += v * v;
        }
        atomicAdd(&sS[j0 + a], s);
        atomicAdd(&sSS[j0 + a], ss);
    }
    #pragma unroll
    for (int b = 0; b < 8; ++b) {
        int e = e0 + eg * 8 + b;
        ushort4 u;
        u.x = f2bf(acc[0][b]); u.y = f2bf(acc[1][b]);
        u.z = f2bf(acc[2][b]); u.w = f2bf(acc[3][b]);
        *(ushort4*)&h1[e * H + j0] = u;
    }
    __syncthreads();
    if (tid < H) { atomicAdd(&gS[tid], sS[tid]); atomicAdd(&gSS[tid], sSS[tid]); }
}

// ---- BN stats -> per-feature scale/shift ----
__global__ void k_stats(const float* __restrict__ S, const float* __restrict__ SS,
                        const float* __restrict__ g, const float* __restrict__ b,
                        float invCount, float* __restrict__ scale, float* __restrict__ shift) {
    int j = threadIdx.x;
    float mu = S[j] * invCount;
    float var = SS[j] * invCount - mu * mu;
    float inv = rsqrtf(var + BN_EPS);
    float sc = inv * g[j];
    scale[j] = sc;
    shift[j] = b[j] - mu * sc;
}

// ---- edge pass 2: msg = relu( relu(bn(h1)) @ W2m + b2m ), atomic scatter into agg[row] ----
__launch_bounds__(256)
__global__ void k_edge2(const unsigned short* __restrict__ h1,
                        const float* __restrict__ scale, const float* __restrict__ shift,
                        const float* __restrict__ W2m, const float* __restrict__ b2m,
                        const int* __restrict__ ei, float* __restrict__ agg) {
    __shared__ float sT[H][68];
    const int tid = threadIdx.x;
    const int e0 = blockIdx.x * 64;
    {
        const int le = tid >> 2, q = tid & 3;
        const int e = e0 + le;
        for (int t = q; t < 32; t += 4) {
            int k0 = 4 * t;
            ushort4 u = *(const ushort4*)&h1[e * H + k0];
            float v0 = fmaxf(fmaf(bf2f(u.x), scale[k0 + 0], shift[k0 + 0]), 0.f);
            float v1 = fmaxf(fmaf(bf2f(u.y), scale[k0 + 1], shift[k0 + 1]), 0.f);
            float v2 = fmaxf(fmaf(bf2f(u.z), scale[k0 + 2], shift[k0 + 2]), 0.f);
            float v3 = fmaxf(fmaf(bf2f(u.w), scale[k0 + 3], shift[k0 + 3]), 0.f);
            sT[k0 + 0][le] = v0; sT[k0 + 1][le] = v1;
            sT[k0 + 2][le] = v2; sT[k0 + 3][le] = v3;
        }
    }
    __syncthreads();
    const int f4 = tid & 31;
    const int eg = tid >> 5;
    float acc[4][8];
    #pragma unroll
    for (int a = 0; a < 4; ++a)
        #pragma unroll
        for (int b = 0; b < 8; ++b) acc[a][b] = 0.f;
    const float4* W4 = (const float4*)W2m;
    #pragma unroll 4
    for (int k = 0; k < H; ++k) {
        float4 w = W4[k * 32 + f4];
        float4 a0 = *(const float4*)&sT[k][eg * 8];
        float4 a1 = *(const float4*)&sT[k][eg * 8 + 4];
        float av[8] = {a0.x, a0.y, a0.z, a0.w, a1.x, a1.y, a1.z, a1.w};
        float wv[4] = {w.x, w.y, w.z, w.w};
        #pragma unroll
        for (int a = 0; a < 4; ++a)
            #pragma unroll
            for (int b = 0; b < 8; ++b) acc[a][b] = fmaf(wv[a], av[b], acc[a][b]);
    }
    const int j0 = 4 * f4;
    float bia0 = b2m[j0], bia1 = b2m[j0 + 1], bia2 = b2m[j0 + 2], bia3 = b2m[j0 + 3];
    #pragma unroll
    for (int b = 0; b < 8; ++b) {
        int e = e0 + eg * 8 + b;
        int row = ei[e];
        float* dst = &agg[row * H + j0];
        atomicAdd(&dst[0], fmaxf(acc[0][b] + bia0, 0.f));
        atomicAdd(&dst[1], fmaxf(acc[1][b] + bia1, 0.f));
        atomicAdd(&dst[2], fmaxf(acc[2][b] + bia2, 0.f));
        atomicAdd(&dst[3], fmaxf(acc[3][b] + bia3, 0.f));
    }
}

// ---- node pass 1: h2 = [x, agg] @ Wn1 + bn1 ; store f32 ; BN stats ----
__launch_bounds__(256)
__global__ void k_node1(const float* __restrict__ x, const float* __restrict__ agg,
                        const float* __restrict__ Wn1, const float* __restrict__ bn1,
                        float* __restrict__ h2, float* __restrict__ gS, float* __restrict__ gSS) {
    __shared__ float sIn[KN][68];
    __shared__ float sS[H], sSS[H];
    const int tid = threadIdx.x;
    const int n0 = blockIdx.x * 64;
    if (tid < H) { sS[tid] = 0.f; sSS[tid] = 0.f; }
    {
        const int ln = tid >> 2, q = tid & 3;
        const int n = n0 + ln;
        const bool valid = n < NNODES;
        const float4* x4 = (const float4*)x;
        const float4* a4 = (const float4*)agg;
        for (int t = q; t < 48; t += 4) {
            float4 v = make_float4(0.f, 0.f, 0.f, 0.f);
            if (valid) v = (t < 16) ? x4[n * 16 + t] : a4[n * 32 + (t - 16)];
            int k0 = 4 * t;
            sIn[k0 + 0][ln] = v.x; sIn[k0 + 1][ln] = v.y;
            sIn[k0 + 2][ln] = v.z; sIn[k0 + 3][ln] = v.w;
        }
    }
    __syncthreads();
    const int f4 = tid & 31;
    const int eg = tid >> 5;
    float acc[4][8];
    #pragma unroll
    for (int a = 0; a < 4; ++a)
        #pragma unroll
        for (int b = 0; b < 8; ++b) acc[a][b] = 0.f;
    const float4* W4 = (const float4*)Wn1;
    #pragma unroll 4
    for (int k = 0; k < KN; ++k) {
        float4 w = W4[k * 32 + f4];
        float4 a0 = *(const float4*)&sIn[k][eg * 8];
        float4 a1 = *(const float4*)&sIn[k][eg * 8 + 4];
        float av[8] = {a0.x, a0.y, a0.z, a0.w, a1.x, a1.y, a1.z, a1.w};
        float wv[4] = {w.x, w.y, w.z, w.w};
        #pragma unroll
        for (int a = 0; a < 4; ++a)
            #pragma unroll
            for (int b = 0; b < 8; ++b) acc[a][b] = fmaf(wv[a], av[b], acc[a][b]);
    }
    const int j0 = 4 * f4;
    #pragma unroll
    for (int a = 0; a < 4; ++a) {
        float bia = bn1[j0 + a];
        float s = 0.f, ss = 0.f;
        #pragma unroll
        for (int b = 0; b < 8; ++b) {
            int n = n0 + eg * 8 + b;
            float v = acc[a][b] + bia;
            acc[a][b] = v;
            if (n < NNODES) { s += v; ss += v * v; }
        }
        atomicAdd(&sS[j0 + a], s);
        atomicAdd(&sSS[j0 + a], ss);
    }
    #pragma unroll
    for (int b = 0; b < 8; ++b) {
        int n = n0 + eg * 8 + b;
        if (n < NNODES) {
            float4 v = make_float4(acc[0][b], acc[1][b], acc[2][b], acc[3][b]);
            *(float4*)&h2[n * H + j0] = v;
        }
    }
    __syncthreads();
    if (tid < H) { atomicAdd(&gS[tid], sS[tid]); atomicAdd(&gSS[tid], sSS[tid]); }
}

// ---- node pass 2: out = relu(bn(h2)) @ Wn2 + bn2 ----
__launch_bounds__(256)
__global__ void k_node2(const float* __restrict__ h2, const float* __restrict__ scale,
                        const float* __restrict__ shift, const float* __restrict__ Wn2,
                        const float* __restrict__ bn2, float* __restrict__ out) {
    __shared__ float sT[H][68];
    const int tid = threadIdx.x;
    const int n0 = blockIdx.x * 64;
    {
        const int ln = tid >> 2, q = tid & 3;
        const int n = n0 + ln;
        const bool valid = n < NNODES;
        for (int t = q; t < 32; t += 4) {
            int k0 = 4 * t;
            float4 v = make_float4(0.f, 0.f, 0.f, 0.f);
            if (valid) v = *(const float4*)&h2[n * H + k0];
            sT[k0 + 0][ln] = fmaxf(fmaf(v.x, scale[k0 + 0], shift[k0 + 0]), 0.f);
            sT[k0 + 1][ln] = fmaxf(fmaf(v.y, scale[k0 + 1], shift[k0 + 1]), 0.f);
            sT[k0 + 2][ln] = fmaxf(fmaf(v.z, scale[k0 + 2], shift[k0 + 2]), 0.f);
            sT[k0 + 3][ln] = fmaxf(fmaf(v.w, scale[k0 + 3], shift[k0 + 3]), 0.f);
        }
    }
    __syncthreads();
    const int f4 = tid & 31;
    const int eg = tid >> 5;
    float acc[4][8];
    #pragma unroll
    for (int a = 0; a < 4; ++a)
        #pragma unroll
        for (int b = 0; b < 8; ++b) acc[a][b] = 0.f;
    const float4* W4 = (const float4*)Wn2;
    #pragma unroll 4
    for (int k = 0; k < H; ++k) {
        float4 w = W4[k * 32 + f4];
        float4 a0 = *(const float4*)&sT[k][eg * 8];
        float4 a1 = *(const float4*)&sT[k][eg * 8 + 4];
        float av[8] = {a0.x, a0.y, a0.z, a0.w, a1.x, a1.y, a1.z, a1.w};
        float wv[4] = {w.x, w.y, w.z, w.w};
        #pragma unroll
        for (int a = 0; a < 4; ++a)
            #pragma unroll
            for (int b = 0; b < 8; ++b) acc[a][b] = fmaf(wv[a], av[b], acc[a][b]);
    }
    const int j0 = 4 * f4;
    float b0 = bn2[j0], b1 = bn2[j0 + 1], b2 = bn2[j0 + 2], b3 = bn2[j0 + 3];
    #pragma unroll
    for (int b = 0; b < 8; ++b) {
        int n = n0 + eg * 8 + b;
        if (n < NNODES) {
            float4 v = make_float4(acc[0][b] + b0, acc[1][b] + b1, acc[2][b] + b2, acc[3][b] + b3);
            *(float4*)&out[n * H + j0] = v;
        }
    }
}

extern "C" void kernel_launch(void* const* d_in, const int* in_sizes, int n_in,
                              void* d_out, int out_size, void* d_ws, size_t ws_size,
                              hipStream_t stream) {
    (void)in_sizes; (void)n_in; (void)out_size; (void)ws_size;
    const float* x   = (const float*)d_in[0];
    const int*   ei  = (const int*)d_in[1];
    const float* ea  = (const float*)d_in[2];
    const float* We1 = (const float*)d_in[3];
    const float* be1 = (const float*)d_in[4];
    const float* ge  = (const float*)d_in[5];
    const float* bbe = (const float*)d_in[6];
    const float* We2 = (const float*)d_in[7];
    const float* be2 = (const float*)d_in[8];
    const float* Wm  = (const float*)d_in[9];
    const float* bm  = (const float*)d_in[10];
    const float* Wn1 = (const float*)d_in[11];
    const float* bn1 = (const float*)d_in[12];
    const float* gn  = (const float*)d_in[13];
    const float* bbn = (const float*)d_in[14];
    const float* Wn2 = (const float*)d_in[15];
    const float* bn2 = (const float*)d_in[16];
    float* out = (float*)d_out;

    char* ws = (char*)d_ws;
    // layout: h1 bf16 [E,H] | agg f32 [N,H] | h2 f32 [N,H] | stats | scales | W2m | b2m
    unsigned short* h1 = (unsigned short*)(ws);                       // 204,800,000 B
    float* agg  = (float*)(ws + 204800000);                           //  25,600,000 B
    float* h2   = (float*)(ws + 230400000);                           //  25,600,000 B
    float* S1   = (float*)(ws + 256000000);
    float* SS1  = S1 + 128;
    float* S2   = S1 + 256;
    float* SS2  = S1 + 384;
    float* scale1 = S1 + 512;
    float* shift1 = S1 + 640;
    float* scale2 = S1 + 768;
    float* shift2 = S1 + 896;
    float* W2m  = (float*)(ws + 256000000 + 4096);
    float* b2m  = W2m + H * H;

    hipMemsetAsync(agg, 0, (size_t)NNODES * H * sizeof(float), stream);
    hipMemsetAsync(S1, 0, 512 * sizeof(float), stream);

    k_fold<<<H + 1, H, 0, stream>>>(We2, be2, Wm, bm, W2m, b2m);
    k_edge1<<<NEDGES / 64, 256, 0, stream>>>(x, ei, ea, We1, be1, h1, S1, SS1);
    k_stats<<<1, H, 0, stream>>>(S1, SS1, ge, bbe, 1.0f / NEDGES, scale1, shift1);
    k_edge2<<<NEDGES / 64, 256, 0, stream>>>(h1, scale1, shift1, W2m, b2m, ei, agg);
    k_node1<<<(NNODES + 63) / 64, 256, 0, stream>>>(x, agg, Wn1, bn1, h2, S2, SS2);
    k_stats<<<1, H, 0, stream>>>(S2, SS2, gn, bbn, 1.0f / NNODES, scale2, shift2);
    k_node2<<<(NNODES + 63) / 64, 256, 0, stream>>>(h2, scale2, shift2, Wn2, bn2, out);
}

// Round 2
// 1253.549 us; speedup vs baseline: 1.6506x; 1.6506x over previous
//
#include <hip/hip_runtime.h>
#include <stdint.h>

#define NNODES 50000
#define NEDGES 800000
#define ND 64
#define ED 16
#define H 128
#define KE 144   // 2*ND + ED
#define KN 192   // ND + H
#define BN_EPS 1e-5f

__device__ __forceinline__ float bf2f(unsigned short u) {
    unsigned int v = ((unsigned int)u) << 16;
    return __uint_as_float(v);
}
__device__ __forceinline__ unsigned short f2bf(float f) {
    unsigned int x = __float_as_uint(f);
    unsigned int r = (x + 0x7FFFu + ((x >> 16) & 1u)) >> 16;
    return (unsigned short)r;
}

// ---- fold We2@Wm into one 128x128 matrix, b2m = be2@Wm + bm ----
__global__ void k_fold(const float* __restrict__ We2, const float* __restrict__ be2,
                       const float* __restrict__ Wm, const float* __restrict__ bm,
                       float* __restrict__ W2m, float* __restrict__ b2m) {
    int j = threadIdx.x;
    int i = blockIdx.x;
    if (i < H) {
        float acc = 0.f;
        for (int k = 0; k < H; ++k) acc = fmaf(We2[i * H + k], Wm[k * H + j], acc);
        W2m[i * H + j] = acc;
    } else {
        float acc = bm[j];
        for (int k = 0; k < H; ++k) acc = fmaf(be2[k], Wm[k * H + j], acc);
        b2m[j] = acc;
    }
}

// ---- CSR build: count / scan / scatter ----
__global__ void k_count(const int* __restrict__ ei, int* __restrict__ cnt) {
    int e = blockIdx.x * 256 + threadIdx.x;
    if (e < NEDGES) atomicAdd(&cnt[ei[e]], 1);
}

__global__ void k_scan(const int* __restrict__ cnt, int* __restrict__ offsets,
                       int* __restrict__ cursor) {
    __shared__ int buf[1024];
    __shared__ int carry;
    const int tid = threadIdx.x;
    if (tid == 0) carry = 0;
    __syncthreads();
    for (int base = 0; base < NNODES; base += 1024) {
        int i = base + tid;
        int v = (i < NNODES) ? cnt[i] : 0;
        buf[tid] = v;
        __syncthreads();
        #pragma unroll
        for (int off = 1; off < 1024; off <<= 1) {
            int t = (tid >= off) ? buf[tid - off] : 0;
            __syncthreads();
            buf[tid] += t;
            __syncthreads();
        }
        int incl = buf[tid];
        int excl = carry + incl - v;
        if (i < NNODES) { offsets[i] = excl; cursor[i] = excl; }
        __syncthreads();
        if (tid == 1023) carry += incl;
        __syncthreads();
    }
    if (tid == 0) offsets[NNODES] = carry;
}

__global__ void k_scatter(const int* __restrict__ ei, int* __restrict__ cursor,
                          int* __restrict__ elist) {
    int e = blockIdx.x * 256 + threadIdx.x;
    if (e < NEDGES) {
        int p = atomicAdd(&cursor[ei[e]], 1);
        elist[p] = e;
    }
}

// ---- edge pass 1: h1 = [x[row],x[col],ea] @ We1 + be1 ; store bf16 ; accumulate BN stats ----
__launch_bounds__(256)
__global__ void k_edge1(const float* __restrict__ x, const int* __restrict__ ei,
                        const float* __restrict__ ea, const float* __restrict__ We1,
                        const float* __restrict__ be1, unsigned short* __restrict__ h1,
                        float* __restrict__ gS, float* __restrict__ gSS) {
    __shared__ float sIn[KE][68];      // transposed edge-input tile, 64 edges, pad 68
    __shared__ float sS[H], sSS[H];
    const int tid = threadIdx.x;
    const int e0 = blockIdx.x * 64;
    if (tid < H) { sS[tid] = 0.f; sSS[tid] = 0.f; }
    {
        const int le = tid >> 2, q = tid & 3;
        const int e = e0 + le;
        const int row = ei[e], col = ei[NEDGES + e];
        const float4* x4 = (const float4*)x;
        const float4* ea4 = (const float4*)ea;
        for (int t = q; t < 36; t += 4) {
            float4 v;
            if (t < 16)      v = x4[row * 16 + t];
            else if (t < 32) v = x4[col * 16 + (t - 16)];
            else             v = ea4[e * 4 + (t - 32)];
            int k0 = 4 * t;
            sIn[k0 + 0][le] = v.x; sIn[k0 + 1][le] = v.y;
            sIn[k0 + 2][le] = v.z; sIn[k0 + 3][le] = v.w;
        }
    }
    __syncthreads();
    const int f4 = tid & 31;   // features j0 = 4*f4 .. +3
    const int eg = tid >> 5;   // edges eg*8 .. +7
    float acc[4][8];
    #pragma unroll
    for (int a = 0; a < 4; ++a)
        #pragma unroll
        for (int b = 0; b < 8; ++b) acc[a][b] = 0.f;
    const float4* W4 = (const float4*)We1;
    #pragma unroll 4
    for (int k = 0; k < KE; ++k) {
        float4 w = W4[k * 32 + f4];
        float4 a0 = *(const float4*)&sIn[k][eg * 8];
        float4 a1 = *(const float4*)&sIn[k][eg * 8 + 4];
        float av[8] = {a0.x, a0.y, a0.z, a0.w, a1.x, a1.y, a1.z, a1.w};
        float wv[4] = {w.x, w.y, w.z, w.w};
        #pragma unroll
        for (int a = 0; a < 4; ++a)
            #pragma unroll
            for (int b = 0; b < 8; ++b) acc[a][b] = fmaf(wv[a], av[b], acc[a][b]);
    }
    const int j0 = 4 * f4;
    #pragma unroll
    for (int a = 0; a < 4; ++a) {
        float bia = be1[j0 + a];
        float s = 0.f, ss = 0.f;
        #pragma unroll
        for (int b = 0; b < 8; ++b) {
            float v = acc[a][b] + bia;
            acc[a][b] = v;
            s += v; ss += v * v;
        }
        atomicAdd(&sS[j0 + a], s);
        atomicAdd(&sSS[j0 + a], ss);
    }
    #pragma unroll
    for (int b = 0; b < 8; ++b) {
        int e = e0 + eg * 8 + b;
        ushort4 u;
        u.x = f2bf(acc[0][b]); u.y = f2bf(acc[1][b]);
        u.z = f2bf(acc[2][b]); u.w = f2bf(acc[3][b]);
        *(ushort4*)&h1[e * H + j0] = u;
    }
    __syncthreads();
    if (tid < H) { atomicAdd(&gS[tid], sS[tid]); atomicAdd(&gSS[tid], sSS[tid]); }
}

// ---- BN stats -> per-feature scale/shift ----
__global__ void k_stats(const float* __restrict__ S, const float* __restrict__ SS,
                        const float* __restrict__ g, const float* __restrict__ b,
                        float invCount, float* __restrict__ scale, float* __restrict__ shift) {
    int j = threadIdx.x;
    float mu = S[j] * invCount;
    float var = SS[j] * invCount - mu * mu;
    float inv = rsqrtf(var + BN_EPS);
    float sc = inv * g[j];
    scale[j] = sc;
    shift[j] = b[j] - mu * sc;
}

// ---- edge pass 2: msg = relu( relu(bn(h1)) @ W2m + b2m ), write bf16 msg IN PLACE over h1 ----
__launch_bounds__(256)
__global__ void k_edge2(unsigned short* __restrict__ h1,
                        const float* __restrict__ scale, const float* __restrict__ shift,
                        const float* __restrict__ W2m, const float* __restrict__ b2m) {
    __shared__ float sT[H][68];
    const int tid = threadIdx.x;
    const int e0 = blockIdx.x * 64;
    {
        const int le = tid >> 2, q = tid & 3;
        const int e = e0 + le;
        for (int t = q; t < 32; t += 4) {
            int k0 = 4 * t;
            ushort4 u = *(const ushort4*)&h1[e * H + k0];
            float v0 = fmaxf(fmaf(bf2f(u.x), scale[k0 + 0], shift[k0 + 0]), 0.f);
            float v1 = fmaxf(fmaf(bf2f(u.y), scale[k0 + 1], shift[k0 + 1]), 0.f);
            float v2 = fmaxf(fmaf(bf2f(u.z), scale[k0 + 2], shift[k0 + 2]), 0.f);
            float v3 = fmaxf(fmaf(bf2f(u.w), scale[k0 + 3], shift[k0 + 3]), 0.f);
            sT[k0 + 0][le] = v0; sT[k0 + 1][le] = v1;
            sT[k0 + 2][le] = v2; sT[k0 + 3][le] = v3;
        }
    }
    __syncthreads();   // all reads of this block's h1 rows done; safe to overwrite below
    const int f4 = tid & 31;
    const int eg = tid >> 5;
    float acc[4][8];
    #pragma unroll
    for (int a = 0; a < 4; ++a)
        #pragma unroll
        for (int b = 0; b < 8; ++b) acc[a][b] = 0.f;
    const float4* W4 = (const float4*)W2m;
    #pragma unroll 4
    for (int k = 0; k < H; ++k) {
        float4 w = W4[k * 32 + f4];
        float4 a0 = *(const float4*)&sT[k][eg * 8];
        float4 a1 = *(const float4*)&sT[k][eg * 8 + 4];
        float av[8] = {a0.x, a0.y, a0.z, a0.w, a1.x, a1.y, a1.z, a1.w};
        float wv[4] = {w.x, w.y, w.z, w.w};
        #pragma unroll
        for (int a = 0; a < 4; ++a)
            #pragma unroll
            for (int b = 0; b < 8; ++b) acc[a][b] = fmaf(wv[a], av[b], acc[a][b]);
    }
    const int j0 = 4 * f4;
    float bia0 = b2m[j0], bia1 = b2m[j0 + 1], bia2 = b2m[j0 + 2], bia3 = b2m[j0 + 3];
    #pragma unroll
    for (int b = 0; b < 8; ++b) {
        int e = e0 + eg * 8 + b;
        ushort4 u;
        u.x = f2bf(fmaxf(acc[0][b] + bia0, 0.f));
        u.y = f2bf(fmaxf(acc[1][b] + bia1, 0.f));
        u.z = f2bf(fmaxf(acc[2][b] + bia2, 0.f));
        u.w = f2bf(fmaxf(acc[3][b] + bia3, 0.f));
        *(ushort4*)&h1[e * H + j0] = u;
    }
}

// ---- aggregation: one wave per node, gather msg rows via CSR, f32 accumulate ----
__launch_bounds__(256)
__global__ void k_agg(const unsigned short* __restrict__ msg,
                      const int* __restrict__ offsets, const int* __restrict__ elist,
                      float* __restrict__ agg) {
    const int n = blockIdx.x * 4 + (threadIdx.x >> 6);
    const int lane = threadIdx.x & 63;
    const int s = offsets[n], t = offsets[n + 1];
    float a0 = 0.f, a1 = 0.f;
    for (int i = s; i < t; ++i) {
        int e = elist[i];
        ushort2 u = *(const ushort2*)&msg[e * H + lane * 2];
        a0 += bf2f(u.x); a1 += bf2f(u.y);
    }
    float2 o; o.x = a0; o.y = a1;
    *(float2*)&agg[n * H + lane * 2] = o;
}

// ---- node pass 1: h2 = [x, agg] @ Wn1 + bn1 ; store f32 ; BN stats ----
__launch_bounds__(256)
__global__ void k_node1(const float* __restrict__ x, const float* __restrict__ agg,
                        const float* __restrict__ Wn1, const float* __restrict__ bn1,
                        float* __restrict__ h2, float* __restrict__ gS, float* __restrict__ gSS) {
    __shared__ float sIn[KN][68];
    __shared__ float sS[H], sSS[H];
    const int tid = threadIdx.x;
    const int n0 = blockIdx.x * 64;
    if (tid < H) { sS[tid] = 0.f; sSS[tid] = 0.f; }
    {
        const int ln = tid >> 2, q = tid & 3;
        const int n = n0 + ln;
        const bool valid = n < NNODES;
        const float4* x4 = (const float4*)x;
        const float4* a4 = (const float4*)agg;
        for (int t = q; t < 48; t += 4) {
            float4 v = make_float4(0.f, 0.f, 0.f, 0.f);
            if (valid) v = (t < 16) ? x4[n * 16 + t] : a4[n * 32 + (t - 16)];
            int k0 = 4 * t;
            sIn[k0 + 0][ln] = v.x; sIn[k0 + 1][ln] = v.y;
            sIn[k0 + 2][ln] = v.z; sIn[k0 + 3][ln] = v.w;
        }
    }
    __syncthreads();
    const int f4 = tid & 31;
    const int eg = tid >> 5;
    float acc[4][8];
    #pragma unroll
    for (int a = 0; a < 4; ++a)
        #pragma unroll
        for (int b = 0; b < 8; ++b) acc[a][b] = 0.f;
    const float4* W4 = (const float4*)Wn1;
    #pragma unroll 4
    for (int k = 0; k < KN; ++k) {
        float4 w = W4[k * 32 + f4];
        float4 a0 = *(const float4*)&sIn[k][eg * 8];
        float4 a1 = *(const float4*)&sIn[k][eg * 8 + 4];
        float av[8] = {a0.x, a0.y, a0.z, a0.w, a1.x, a1.y, a1.z, a1.w};
        float wv[4] = {w.x, w.y, w.z, w.w};
        #pragma unroll
        for (int a = 0; a < 4; ++a)
            #pragma unroll
            for (int b = 0; b < 8; ++b) acc[a][b] = fmaf(wv[a], av[b], acc[a][b]);
    }
    const int j0 = 4 * f4;
    #pragma unroll
    for (int a = 0; a < 4; ++a) {
        float bia = bn1[j0 + a];
        float s = 0.f, ss = 0.f;
        #pragma unroll
        for (int b = 0; b < 8; ++b) {
            int n = n0 + eg * 8 + b;
            float v = acc[a][b] + bia;
            acc[a][b] = v;
            if (n < NNODES) { s += v; ss += v * v; }
        }
        atomicAdd(&sS[j0 + a], s);
        atomicAdd(&sSS[j0 + a], ss);
    }
    #pragma unroll
    for (int b = 0; b < 8; ++b) {
        int n = n0 + eg * 8 + b;
        if (n < NNODES) {
            float4 v = make_float4(acc[0][b], acc[1][b], acc[2][b], acc[3][b]);
            *(float4*)&h2[n * H + j0] = v;
        }
    }
    __syncthreads();
    if (tid < H) { atomicAdd(&gS[tid], sS[tid]); atomicAdd(&gSS[tid], sSS[tid]); }
}

// ---- node pass 2: out = relu(bn(h2)) @ Wn2 + bn2 ----
__launch_bounds__(256)
__global__ void k_node2(const float* __restrict__ h2, const float* __restrict__ scale,
                        const float* __restrict__ shift, const float* __restrict__ Wn2,
                        const float* __restrict__ bn2, float* __restrict__ out) {
    __shared__ float sT[H][68];
    const int tid = threadIdx.x;
    const int n0 = blockIdx.x * 64;
    {
        const int ln = tid >> 2, q = tid & 3;
        const int n = n0 + ln;
        const bool valid = n < NNODES;
        for (int t = q; t < 32; t += 4) {
            int k0 = 4 * t;
            float4 v = make_float4(0.f, 0.f, 0.f, 0.f);
            if (valid) v = *(const float4*)&h2[n * H + k0];
            sT[k0 + 0][ln] = fmaxf(fmaf(v.x, scale[k0 + 0], shift[k0 + 0]), 0.f);
            sT[k0 + 1][ln] = fmaxf(fmaf(v.y, scale[k0 + 1], shift[k0 + 1]), 0.f);
            sT[k0 + 2][ln] = fmaxf(fmaf(v.z, scale[k0 + 2], shift[k0 + 2]), 0.f);
            sT[k0 + 3][ln] = fmaxf(fmaf(v.w, scale[k0 + 3], shift[k0 + 3]), 0.f);
        }
    }
    __syncthreads();
    const int f4 = tid & 31;
    const int eg = tid >> 5;
    float acc[4][8];
    #pragma unroll
    for (int a = 0; a < 4; ++a)
        #pragma unroll
        for (int b = 0; b < 8; ++b) acc[a][b] = 0.f;
    const float4* W4 = (const float4*)Wn2;
    #pragma unroll 4
    for (int k = 0; k < H; ++k) {
        float4 w = W4[k * 32 + f4];
        float4 a0 = *(const float4*)&sT[k][eg * 8];
        float4 a1 = *(const float4*)&sT[k][eg * 8 + 4];
        float av[8] = {a0.x, a0.y, a0.z, a0.w, a1.x, a1.y, a1.z, a1.w};
        float wv[4] = {w.x, w.y, w.z, w.w};
        #pragma unroll
        for (int a = 0; a < 4; ++a)
            #pragma unroll
            for (int b = 0; b < 8; ++b) acc[a][b] = fmaf(wv[a], av[b], acc[a][b]);
    }
    const int j0 = 4 * f4;
    float b0 = bn2[j0], b1 = bn2[j0 + 1], b2 = bn2[j0 + 2], b3 = bn2[j0 + 3];
    #pragma unroll
    for (int b = 0; b < 8; ++b) {
        int n = n0 + eg * 8 + b;
        if (n < NNODES) {
            float4 v = make_float4(acc[0][b] + b0, acc[1][b] + b1, acc[2][b] + b2, acc[3][b] + b3);
            *(float4*)&out[n * H + j0] = v;
        }
    }
}

extern "C" void kernel_launch(void* const* d_in, const int* in_sizes, int n_in,
                              void* d_out, int out_size, void* d_ws, size_t ws_size,
                              hipStream_t stream) {
    (void)in_sizes; (void)n_in; (void)out_size; (void)ws_size;
    const float* x   = (const float*)d_in[0];
    const int*   ei  = (const int*)d_in[1];
    const float* ea  = (const float*)d_in[2];
    const float* We1 = (const float*)d_in[3];
    const float* be1 = (const float*)d_in[4];
    const float* ge  = (const float*)d_in[5];
    const float* bbe = (const float*)d_in[6];
    const float* We2 = (const float*)d_in[7];
    const float* be2 = (const float*)d_in[8];
    const float* Wm  = (const float*)d_in[9];
    const float* bm  = (const float*)d_in[10];
    const float* Wn1 = (const float*)d_in[11];
    const float* bn1 = (const float*)d_in[12];
    const float* gn  = (const float*)d_in[13];
    const float* bbn = (const float*)d_in[14];
    const float* Wn2 = (const float*)d_in[15];
    const float* bn2 = (const float*)d_in[16];
    float* out = (float*)d_out;

    char* ws = (char*)d_ws;
    // layout:
    //   [0, 204.8MB)          h1/msg bf16 [E,H]; ALSO h2 f32 [N,H] (reused after k_agg)
    //   [204.8MB, 230.4MB)    agg f32 [N,H]
    //   [230.4MB, +4KB)       BN stats + scale/shift
    //   [+4KB, +70KB)         W2m, b2m
    //   [~230.47MB, ~234.3MB) CSR: cnt, offsets, cursor, elist
    unsigned short* h1 = (unsigned short*)(ws);
    float* h2   = (float*)(ws);                       // overlaps h1 (h1/msg dead after k_agg)
    float* agg  = (float*)(ws + 204800000);
    float* S1   = (float*)(ws + 230400000);
    float* SS1  = S1 + 128;
    float* S2   = S1 + 256;
    float* SS2  = S1 + 384;
    float* scale1 = S1 + 512;
    float* shift1 = S1 + 640;
    float* scale2 = S1 + 768;
    float* shift2 = S1 + 896;
    float* W2m  = (float*)(ws + 230404096);
    float* b2m  = W2m + H * H;
    int* cnt     = (int*)(ws + 230470656);
    int* offsets = cnt + 50000;        // needs NNODES+1 entries
    int* cursor  = offsets + 50432;
    int* elist   = cursor + 50000;     // 800000 entries

    hipMemsetAsync(cnt, 0, NNODES * sizeof(int), stream);
    hipMemsetAsync(S1, 0, 512 * sizeof(float), stream);

    k_fold<<<H + 1, H, 0, stream>>>(We2, be2, Wm, bm, W2m, b2m);
    k_count<<<NEDGES / 256, 256, 0, stream>>>(ei, cnt);
    k_scan<<<1, 1024, 0, stream>>>(cnt, offsets, cursor);
    k_scatter<<<NEDGES / 256, 256, 0, stream>>>(ei, cursor, elist);
    k_edge1<<<NEDGES / 64, 256, 0, stream>>>(x, ei, ea, We1, be1, h1, S1, SS1);
    k_stats<<<1, H, 0, stream>>>(S1, SS1, ge, bbe, 1.0f / NEDGES, scale1, shift1);
    k_edge2<<<NEDGES / 64, 256, 0, stream>>>(h1, scale1, shift1, W2m, b2m);
    k_agg<<<NNODES / 4, 256, 0, stream>>>(h1, offsets, elist, agg);
    k_node1<<<(NNODES + 63) / 64, 256, 0, stream>>>(x, agg, Wn1, bn1, h2, S2, SS2);
    k_stats<<<1, H, 0, stream>>>(S2, SS2, gn, bbn, 1.0f / NNODES, scale2, shift2);
    k_node2<<<(NNODES + 63) / 64, 256, 0, stream>>>(h2, scale2, shift2, Wn2, bn2, out);
}

// Round 3
// 750.960 us; speedup vs baseline: 2.7553x; 1.6693x over previous
//
#include <hip/hip_runtime.h>
#include <stdint.h>

#define NNODES 50000
#define NEDGES 800000
#define H 128
#define BN_EPS 1e-5f

typedef short short8 __attribute__((ext_vector_type(8)));
typedef float f32x4 __attribute__((ext_vector_type(4)));

__device__ __forceinline__ float bf2f(unsigned short u) {
    unsigned int v = ((unsigned int)u) << 16;
    return __uint_as_float(v);
}
__device__ __forceinline__ unsigned short f2bf(float f) {
    unsigned int x = __float_as_uint(f);
    return (unsigned short)((x + 0x7FFFu + ((x >> 16) & 1u)) >> 16);
}
__device__ __forceinline__ short8 s8z() { short8 z = {0,0,0,0,0,0,0,0}; return z; }

// ================= common MFMA tile core =================
// Block tile: 128 rows (LDS, bf16, stride SK shorts) x 128 cols.
// Wave w: rows m0=(w&1)*64, cols n0=(w>>1)*64 (n0 may carry a global offset).
// B streamed from global WT[n][k] (bf16, row length RK shorts), L2-hot.
template<int KB>
__device__ __forceinline__ void gemm_tile(const short* __restrict__ sA, const int SK,
                                          const unsigned short* __restrict__ WT, const int RK,
                                          const int n0, f32x4 acc[4][4], const int lane) {
    const int mr = lane & 15, quad = lane >> 4;
    const short* W = (const short*)WT;
    #pragma unroll
    for (int kb = 0; kb < KB; ++kb) {
        short8 a[4];
        #pragma unroll
        for (int mt = 0; mt < 4; ++mt)
            a[mt] = *(const short8*)&sA[(mt*16 + mr)*SK + kb*32 + quad*8];
        #pragma unroll
        for (int nt = 0; nt < 4; ++nt) {
            short8 b = *(const short8*)&W[(size_t)(n0 + nt*16 + mr)*RK + kb*32 + quad*8];
            #pragma unroll
            for (int mt = 0; mt < 4; ++mt)
                acc[mt][nt] = __builtin_amdgcn_mfma_f32_16x16x32_bf16(a[mt], b, acc[mt][nt], 0, 0, 0);
        }
    }
}

// ---- fold We2@Wm -> W2m (f32), b2m = be2@Wm + bm ----
__global__ void k_fold(const float* __restrict__ We2, const float* __restrict__ be2,
                       const float* __restrict__ Wm, const float* __restrict__ bm,
                       float* __restrict__ W2m, float* __restrict__ b2m) {
    int j = threadIdx.x;
    int i = blockIdx.x;
    if (i < H) {
        float acc = 0.f;
        for (int k = 0; k < H; ++k) acc = fmaf(We2[i*H + k], Wm[k*H + j], acc);
        W2m[i*H + j] = acc;
    } else {
        float acc = bm[j];
        for (int k = 0; k < H; ++k) acc = fmaf(be2[k], Wm[k*H + j], acc);
        b2m[j] = acc;
    }
}

// ---- transposed bf16 weight copies for MFMA B-frags ----
__global__ void k_prep2(const float* __restrict__ We1, const float* __restrict__ Wn1,
                        const float* __restrict__ Wn2, const float* __restrict__ W2m,
                        unsigned short* __restrict__ WabT, unsigned short* __restrict__ Wn1T,
                        unsigned short* __restrict__ Wn2T, unsigned short* __restrict__ W2mT) {
    int i = blockIdx.x*256 + threadIdx.x;
    if (i < 16384) {                        // WabT[256][64]: n<128 -> We1 rows 0..63 ; else rows 64..127
        int n = i >> 6, k = i & 63;
        WabT[n*64 + k] = f2bf(We1[(n < 128 ? k : 64 + k)*H + (n & 127)]);
    } else if (i < 40960) {                 // Wn1T[128][192]
        int j = i - 16384; int n = j / 192, k = j - n*192;
        Wn1T[n*192 + k] = f2bf(Wn1[k*H + n]);
    } else if (i < 57344) {                 // Wn2T[128][128]
        int j = i - 40960; int n = j >> 7, k = j & 127;
        Wn2T[n*H + k] = f2bf(Wn2[k*H + n]);
    } else if (i < 73728) {                 // W2mT[128][128]
        int j = i - 57344; int n = j >> 7, k = j & 127;
        W2mT[n*H + k] = f2bf(W2m[k*H + n]);
    }
}

// ---- CSR build ----
__global__ void k_count(const int* __restrict__ ei, int* __restrict__ cnt) {
    int e = blockIdx.x*256 + threadIdx.x;
    if (e < NEDGES) atomicAdd(&cnt[ei[e]], 1);
}

__global__ void k_scan(const int* __restrict__ cnt, int* __restrict__ offsets,
                       int* __restrict__ cursor) {
    __shared__ int wsum[16];
    __shared__ int carry;
    const int tid = threadIdx.x;
    const int lane = tid & 63, wid = tid >> 6;
    if (tid == 0) carry = 0;
    for (int base = 0; base < NNODES; base += 1024) {
        int i = base + tid;
        int v = (i < NNODES) ? cnt[i] : 0;
        int xv = v;
        #pragma unroll
        for (int off = 1; off < 64; off <<= 1) {
            int y = __shfl_up(xv, off);
            if (lane >= off) xv += y;
        }
        if (lane == 63) wsum[wid] = xv;
        __syncthreads();
        if (tid == 0) {
            int a = carry;
            #pragma unroll
            for (int j = 0; j < 16; ++j) { int t = wsum[j]; wsum[j] = a; a += t; }
            carry = a;
        }
        __syncthreads();
        int excl = wsum[wid] + xv - v;
        if (i < NNODES) { offsets[i] = excl; cursor[i] = excl; }
        __syncthreads();
    }
    if (tid == 0) offsets[NNODES] = carry;
}

__global__ void k_scatter(const int* __restrict__ ei, int* __restrict__ cursor,
                          int* __restrict__ elist) {
    int e = blockIdx.x*256 + threadIdx.x;
    if (e < NEDGES) {
        int p = atomicAdd(&cursor[ei[e]], 1);
        elist[p] = e;
    }
}

// ---- T = x @ [Wa | Wb]  (bf16 out, [50000][256]) ----
__launch_bounds__(256)
__global__ void k_T(const float* __restrict__ x, const unsigned short* __restrict__ WabT,
                    unsigned short* __restrict__ T) {
    __shared__ short sA[128*72];
    const int tid = threadIdx.x;
    const int n0b = blockIdx.x*128;
    {
        const int rowl = tid >> 1, half = (tid & 1)*32;
        const int node = n0b + rowl;
        const bool ok = node < NNODES;
        #pragma unroll
        for (int c = 0; c < 4; ++c) {
            int k0 = half + c*8;
            short8 o = s8z();
            if (ok) {
                float4 a = *(const float4*)&x[node*64 + k0];
                float4 b = *(const float4*)&x[node*64 + k0 + 4];
                o[0]=(short)f2bf(a.x); o[1]=(short)f2bf(a.y); o[2]=(short)f2bf(a.z); o[3]=(short)f2bf(a.w);
                o[4]=(short)f2bf(b.x); o[5]=(short)f2bf(b.y); o[6]=(short)f2bf(b.z); o[7]=(short)f2bf(b.w);
            }
            *(short8*)&sA[rowl*72 + k0] = o;
        }
    }
    __syncthreads();
    const int wave = tid >> 6, lane = tid & 63;
    const int m0 = (wave & 1)*64;
    const int n0 = blockIdx.y*128 + (wave >> 1)*64;   // absolute col in [0,256)
    f32x4 acc[4][4];
    f32x4 z = {0.f, 0.f, 0.f, 0.f};
    #pragma unroll
    for (int mt = 0; mt < 4; ++mt)
        #pragma unroll
        for (int nt = 0; nt < 4; ++nt) acc[mt][nt] = z;
    gemm_tile<2>(sA + m0*72, 72, WabT, 64, n0, acc, lane);
    const int mr = lane & 15, quad = lane >> 4;
    #pragma unroll
    for (int nt = 0; nt < 4; ++nt) {
        int j = n0 + nt*16 + mr;
        #pragma unroll
        for (int mt = 0; mt < 4; ++mt) {
            int nb = n0b + m0 + mt*16 + quad*4;
            #pragma unroll
            for (int r = 0; r < 4; ++r) {
                int node = nb + r;
                if (node < NNODES) T[(size_t)node*256 + j] = f2bf(acc[mt][nt][r]);
            }
        }
    }
}

// ---- h1[e] = T1[row] + T2[col] + ea@Wc + be1 ; bf16 store ; BN stats ----
// 16 lanes/edge, Wc (16x8 per lane) in registers, 20000 slots x 40 edges.
__launch_bounds__(256)
__global__ void k_gather(const unsigned short* __restrict__ T, const int* __restrict__ ei,
                         const float* __restrict__ ea, const float* __restrict__ We1,
                         const float* __restrict__ be1, unsigned short* __restrict__ h1,
                         float* __restrict__ gS, float* __restrict__ gSS) {
    __shared__ float sS[H], sSS[H];
    const int tid = threadIdx.x;
    if (tid < H) { sS[tid] = 0.f; sSS[tid] = 0.f; }
    const int li = tid & 15;
    const int slot = (blockIdx.x*256 + tid) >> 4;      // 0..19999
    float4 wcA[16], wcB[16];
    #pragma unroll
    for (int k = 0; k < 16; ++k) {
        wcA[k] = *(const float4*)&We1[(128 + k)*H + li*8];
        wcB[k] = *(const float4*)&We1[(128 + k)*H + li*8 + 4];
    }
    float be[8];
    #pragma unroll
    for (int i = 0; i < 8; ++i) be[i] = be1[li*8 + i];
    float s[8], ss[8];
    #pragma unroll
    for (int i = 0; i < 8; ++i) { s[i] = 0.f; ss[i] = 0.f; }
    for (int it = 0; it < 40; ++it) {
        int e = slot + it*20000;
        int row = ei[e], col = ei[NEDGES + e];
        short8 t1 = *(const short8*)&T[(size_t)row*256 + li*8];
        short8 t2 = *(const short8*)&T[(size_t)col*256 + 128 + li*8];
        float v[8];
        #pragma unroll
        for (int i = 0; i < 8; ++i)
            v[i] = bf2f((unsigned short)t1[i]) + bf2f((unsigned short)t2[i]) + be[i];
        #pragma unroll
        for (int k = 0; k < 16; ++k) {
            float a = ea[e*16 + k];
            v[0] = fmaf(a, wcA[k].x, v[0]); v[1] = fmaf(a, wcA[k].y, v[1]);
            v[2] = fmaf(a, wcA[k].z, v[2]); v[3] = fmaf(a, wcA[k].w, v[3]);
            v[4] = fmaf(a, wcB[k].x, v[4]); v[5] = fmaf(a, wcB[k].y, v[5]);
            v[6] = fmaf(a, wcB[k].z, v[6]); v[7] = fmaf(a, wcB[k].w, v[7]);
        }
        short8 o;
        #pragma unroll
        for (int i = 0; i < 8; ++i) {
            o[i] = (short)f2bf(v[i]);
            s[i] += v[i]; ss[i] += v[i]*v[i];
        }
        *(short8*)&h1[(size_t)e*H + li*8] = o;
    }
    __syncthreads();
    #pragma unroll
    for (int i = 0; i < 8; ++i) {
        atomicAdd(&sS[li*8 + i], s[i]);
        atomicAdd(&sSS[li*8 + i], ss[i]);
    }
    __syncthreads();
    if (tid < H) { atomicAdd(&gS[tid], sS[tid]); atomicAdd(&gSS[tid], sSS[tid]); }
}

// ---- BN stats -> scale/shift ----
__global__ void k_stats(const float* __restrict__ S, const float* __restrict__ SS,
                        const float* __restrict__ g, const float* __restrict__ b,
                        float invCount, float* __restrict__ scale, float* __restrict__ shift) {
    int j = threadIdx.x;
    float mu = S[j]*invCount;
    float var = SS[j]*invCount - mu*mu;
    float sc = rsqrtf(var + BN_EPS)*g[j];
    scale[j] = sc;
    shift[j] = b[j] - mu*sc;
}

// ---- msg = relu( relu(bn(h1)) @ W2m + b2m ) ; bf16, in place over h1 ----
__launch_bounds__(256)
__global__ void k_edge2(unsigned short* __restrict__ hb,
                        const float* __restrict__ scale, const float* __restrict__ shift,
                        const unsigned short* __restrict__ W2mT, const float* __restrict__ b2m) {
    __shared__ short sA[128*136];
    const int tid = threadIdx.x;
    const size_t e0 = (size_t)blockIdx.x*128;
    {
        const int rowl = tid >> 1, half = (tid & 1)*64;
        const size_t base = (e0 + rowl)*H + half;
        #pragma unroll
        for (int c = 0; c < 8; ++c) {
            int k0 = half + c*8;
            short8 raw = *(const short8*)&hb[base + c*8];
            float4 sc0 = *(const float4*)&scale[k0], sc1 = *(const float4*)&scale[k0 + 4];
            float4 sh0 = *(const float4*)&shift[k0], sh1 = *(const float4*)&shift[k0 + 4];
            short8 o;
            o[0] = (short)f2bf(fmaxf(fmaf(bf2f((unsigned short)raw[0]), sc0.x, sh0.x), 0.f));
            o[1] = (short)f2bf(fmaxf(fmaf(bf2f((unsigned short)raw[1]), sc0.y, sh0.y), 0.f));
            o[2] = (short)f2bf(fmaxf(fmaf(bf2f((unsigned short)raw[2]), sc0.z, sh0.z), 0.f));
            o[3] = (short)f2bf(fmaxf(fmaf(bf2f((unsigned short)raw[3]), sc0.w, sh0.w), 0.f));
            o[4] = (short)f2bf(fmaxf(fmaf(bf2f((unsigned short)raw[4]), sc1.x, sh1.x), 0.f));
            o[5] = (short)f2bf(fmaxf(fmaf(bf2f((unsigned short)raw[5]), sc1.y, sh1.y), 0.f));
            o[6] = (short)f2bf(fmaxf(fmaf(bf2f((unsigned short)raw[6]), sc1.z, sh1.z), 0.f));
            o[7] = (short)f2bf(fmaxf(fmaf(bf2f((unsigned short)raw[7]), sc1.w, sh1.w), 0.f));
            *(short8*)&sA[rowl*136 + k0] = o;
        }
    }
    __syncthreads();
    const int wave = tid >> 6, lane = tid & 63;
    const int m0 = (wave & 1)*64, n0 = (wave >> 1)*64;
    f32x4 acc[4][4];
    f32x4 z = {0.f, 0.f, 0.f, 0.f};
    #pragma unroll
    for (int mt = 0; mt < 4; ++mt)
        #pragma unroll
        for (int nt = 0; nt < 4; ++nt) acc[mt][nt] = z;
    gemm_tile<4>(sA + m0*136, 136, W2mT, 128, n0, acc, lane);
    const int mr = lane & 15, quad = lane >> 4;
    #pragma unroll
    for (int nt = 0; nt < 4; ++nt) {
        int j = n0 + nt*16 + mr;
        float bias = b2m[j];
        #pragma unroll
        for (int mt = 0; mt < 4; ++mt) {
            size_t eb = e0 + m0 + mt*16 + quad*4;
            #pragma unroll
            for (int r = 0; r < 4; ++r)
                hb[(eb + r)*H + j] = f2bf(fmaxf(acc[mt][nt][r] + bias, 0.f));
        }
    }
}

// ---- aggregation: one wave per node, CSR gather, f32 accumulate, bf16 store ----
__launch_bounds__(256)
__global__ void k_agg(const unsigned short* __restrict__ msg, const int* __restrict__ offsets,
                      const int* __restrict__ elist, unsigned short* __restrict__ aggb) {
    const int n = blockIdx.x*4 + (threadIdx.x >> 6);
    const int lane = threadIdx.x & 63;
    const int s0 = offsets[n], t0 = offsets[n + 1];
    float a0 = 0.f, a1 = 0.f;
    for (int i = s0; i < t0; ++i) {
        int e = elist[i];
        unsigned int u = *(const unsigned int*)&msg[(size_t)e*H + lane*2];
        a0 += bf2f((unsigned short)(u & 0xFFFFu));
        a1 += bf2f((unsigned short)(u >> 16));
    }
    unsigned int o = (unsigned int)f2bf(a0) | ((unsigned int)f2bf(a1) << 16);
    *(unsigned int*)&aggb[(size_t)n*H + lane*2] = o;
}

// ---- h2 = [x, agg] @ Wn1 + bn1 (f32 store) ; BN stats ----
__launch_bounds__(256)
__global__ void k_node1(const float* __restrict__ x, const unsigned short* __restrict__ aggb,
                        const unsigned short* __restrict__ Wn1T, const float* __restrict__ bn1,
                        float* __restrict__ h2, float* __restrict__ gS, float* __restrict__ gSS) {
    __shared__ short sA[128*200];
    __shared__ float sS[H], sSS[H];
    const int tid = threadIdx.x;
    if (tid < H) { sS[tid] = 0.f; sSS[tid] = 0.f; }
    const int n0b = blockIdx.x*128;
    {
        const int rowl = tid >> 1, half = (tid & 1)*96;
        const int node = n0b + rowl;
        const bool ok = node < NNODES;
        #pragma unroll
        for (int c = 0; c < 12; ++c) {
            int k0 = half + c*8;
            short8 o = s8z();
            if (ok) {
                if (k0 < 64) {
                    float4 a = *(const float4*)&x[node*64 + k0];
                    float4 b = *(const float4*)&x[node*64 + k0 + 4];
                    o[0]=(short)f2bf(a.x); o[1]=(short)f2bf(a.y); o[2]=(short)f2bf(a.z); o[3]=(short)f2bf(a.w);
                    o[4]=(short)f2bf(b.x); o[5]=(short)f2bf(b.y); o[6]=(short)f2bf(b.z); o[7]=(short)f2bf(b.w);
                } else {
                    o = *(const short8*)&aggb[(size_t)node*H + (k0 - 64)];
                }
            }
            *(short8*)&sA[rowl*200 + k0] = o;
        }
    }
    __syncthreads();
    const int wave = tid >> 6, lane = tid & 63;
    const int m0 = (wave & 1)*64, n0 = (wave >> 1)*64;
    f32x4 acc[4][4];
    f32x4 z = {0.f, 0.f, 0.f, 0.f};
    #pragma unroll
    for (int mt = 0; mt < 4; ++mt)
        #pragma unroll
        for (int nt = 0; nt < 4; ++nt) acc[mt][nt] = z;
    gemm_tile<6>(sA + m0*200, 200, Wn1T, 192, n0, acc, lane);
    const int mr = lane & 15, quad = lane >> 4;
    #pragma unroll
    for (int nt = 0; nt < 4; ++nt) {
        int j = n0 + nt*16 + mr;
        float bias = bn1[j];
        float s = 0.f, ssum = 0.f;
        #pragma unroll
        for (int mt = 0; mt < 4; ++mt) {
            int nb = n0b + m0 + mt*16 + quad*4;
            #pragma unroll
            for (int r = 0; r < 4; ++r) {
                int node = nb + r;
                if (node < NNODES) {
                    float v = acc[mt][nt][r] + bias;
                    h2[(size_t)node*H + j] = v;
                    s += v; ssum += v*v;
                }
            }
        }
        atomicAdd(&sS[j], s);
        atomicAdd(&sSS[j], ssum);
    }
    __syncthreads();
    if (tid < H) { atomicAdd(&gS[tid], sS[tid]); atomicAdd(&gSS[tid], sSS[tid]); }
}

// ---- out = relu(bn(h2)) @ Wn2 + bn2 (f32) ----
__launch_bounds__(256)
__global__ void k_node2(const float* __restrict__ h2, const float* __restrict__ scale,
                        const float* __restrict__ shift, const unsigned short* __restrict__ Wn2T,
                        const float* __restrict__ bn2, float* __restrict__ out) {
    __shared__ short sA[128*136];
    const int tid = threadIdx.x;
    const int n0b = blockIdx.x*128;
    {
        const int rowl = tid >> 1, half = (tid & 1)*64;
        const int node = n0b + rowl;
        const bool ok = node < NNODES;
        #pragma unroll
        for (int c = 0; c < 8; ++c) {
            int k0 = half + c*8;
            short8 o = s8z();
            if (ok) {
                float4 a = *(const float4*)&h2[(size_t)node*H + k0];
                float4 b = *(const float4*)&h2[(size_t)node*H + k0 + 4];
                float4 sc0 = *(const float4*)&scale[k0], sc1 = *(const float4*)&scale[k0 + 4];
                float4 sh0 = *(const float4*)&shift[k0], sh1 = *(const float4*)&shift[k0 + 4];
                o[0] = (short)f2bf(fmaxf(fmaf(a.x, sc0.x, sh0.x), 0.f));
                o[1] = (short)f2bf(fmaxf(fmaf(a.y, sc0.y, sh0.y), 0.f));
                o[2] = (short)f2bf(fmaxf(fmaf(a.z, sc0.z, sh0.z), 0.f));
                o[3] = (short)f2bf(fmaxf(fmaf(a.w, sc0.w, sh0.w), 0.f));
                o[4] = (short)f2bf(fmaxf(fmaf(b.x, sc1.x, sh1.x), 0.f));
                o[5] = (short)f2bf(fmaxf(fmaf(b.y, sc1.y, sh1.y), 0.f));
                o[6] = (short)f2bf(fmaxf(fmaf(b.z, sc1.z, sh1.z), 0.f));
                o[7] = (short)f2bf(fmaxf(fmaf(b.w, sc1.w, sh1.w), 0.f));
            }
            *(short8*)&sA[rowl*136 + k0] = o;
        }
    }
    __syncthreads();
    const int wave = tid >> 6, lane = tid & 63;
    const int m0 = (wave & 1)*64, n0 = (wave >> 1)*64;
    f32x4 acc[4][4];
    f32x4 z = {0.f, 0.f, 0.f, 0.f};
    #pragma unroll
    for (int mt = 0; mt < 4; ++mt)
        #pragma unroll
        for (int nt = 0; nt < 4; ++nt) acc[mt][nt] = z;
    gemm_tile<4>(sA + m0*136, 136, Wn2T, 128, n0, acc, lane);
    const int mr = lane & 15, quad = lane >> 4;
    #pragma unroll
    for (int nt = 0; nt < 4; ++nt) {
        int j = n0 + nt*16 + mr;
        float bias = bn2[j];
        #pragma unroll
        for (int mt = 0; mt < 4; ++mt) {
            int nb = n0b + m0 + mt*16 + quad*4;
            #pragma unroll
            for (int r = 0; r < 4; ++r) {
                int node = nb + r;
                if (node < NNODES) out[(size_t)node*H + j] = acc[mt][nt][r] + bias;
            }
        }
    }
}

extern "C" void kernel_launch(void* const* d_in, const int* in_sizes, int n_in,
                              void* d_out, int out_size, void* d_ws, size_t ws_size,
                              hipStream_t stream) {
    (void)in_sizes; (void)n_in; (void)out_size; (void)ws_size;
    const float* x   = (const float*)d_in[0];
    const int*   ei  = (const int*)d_in[1];
    const float* ea  = (const float*)d_in[2];
    const float* We1 = (const float*)d_in[3];
    const float* be1 = (const float*)d_in[4];
    const float* ge  = (const float*)d_in[5];
    const float* bbe = (const float*)d_in[6];
    const float* We2 = (const float*)d_in[7];
    const float* be2 = (const float*)d_in[8];
    const float* Wm  = (const float*)d_in[9];
    const float* bm  = (const float*)d_in[10];
    const float* Wn1 = (const float*)d_in[11];
    const float* bn1 = (const float*)d_in[12];
    const float* gn  = (const float*)d_in[13];
    const float* bbn = (const float*)d_in[14];
    const float* Wn2 = (const float*)d_in[15];
    const float* bn2 = (const float*)d_in[16];
    float* out = (float*)d_out;

    char* ws = (char*)d_ws;
    // [0, 204.8M)            h1 / msg (in place) bf16 [E][128]
    // [204.8M, 217.6M)       agg bf16 [N][128]
    // [217.6M, 243.2M)       T bf16 [N][256]  (h2 f32 [N][128] overlays after k_gather)
    // [243.2M, ~247M)        CSR
    // [~247M, ~247.3M)       stats, W2m, b2m, transposed bf16 weights
    unsigned short* hb   = (unsigned short*)(ws);
    unsigned short* aggb = (unsigned short*)(ws + 204800000);
    unsigned short* Tbuf = (unsigned short*)(ws + 217600000);
    float*          h2   = (float*)(ws + 217600000);
    int* cnt     = (int*)(ws + 243200000);
    int* offsets = (int*)(ws + 243400000);
    int* cursor  = (int*)(ws + 243600064);
    int* elist   = (int*)(ws + 243800064);
    float* S1     = (float*)(ws + 247000064);
    float* SS1    = S1 + 128;
    float* S2     = S1 + 256;
    float* SS2    = S1 + 384;
    float* scale1 = S1 + 512;
    float* shift1 = S1 + 640;
    float* scale2 = S1 + 768;
    float* shift2 = S1 + 896;
    float* W2m = (float*)(ws + 247004160);
    float* b2m = (float*)(ws + 247069696);
    unsigned short* WabT = (unsigned short*)(ws + 247070208);
    unsigned short* Wn1T = (unsigned short*)(ws + 247102976);
    unsigned short* Wn2T = (unsigned short*)(ws + 247152128);
    unsigned short* W2mT = (unsigned short*)(ws + 247184896);

    hipMemsetAsync(cnt, 0, NNODES*sizeof(int), stream);
    hipMemsetAsync(S1, 0, 512*sizeof(float), stream);

    k_fold<<<H + 1, H, 0, stream>>>(We2, be2, Wm, bm, W2m, b2m);
    k_prep2<<<288, 256, 0, stream>>>(We1, Wn1, Wn2, W2m, WabT, Wn1T, Wn2T, W2mT);
    k_count<<<NEDGES/256, 256, 0, stream>>>(ei, cnt);
    k_scan<<<1, 1024, 0, stream>>>(cnt, offsets, cursor);
    k_scatter<<<NEDGES/256, 256, 0, stream>>>(ei, cursor, elist);
    k_T<<<dim3(391, 2), 256, 0, stream>>>(x, WabT, Tbuf);
    k_gather<<<1250, 256, 0, stream>>>(Tbuf, ei, ea, We1, be1, hb, S1, SS1);
    k_stats<<<1, H, 0, stream>>>(S1, SS1, ge, bbe, 1.0f/NEDGES, scale1, shift1);
    k_edge2<<<NEDGES/128, 256, 0, stream>>>(hb, scale1, shift1, W2mT, b2m);
    k_agg<<<NNODES/4, 256, 0, stream>>>(hb, offsets, elist, aggb);
    k_node1<<<391, 256, 0, stream>>>(x, aggb, Wn1T, bn1, h2, S2, SS2);
    k_stats<<<1, H, 0, stream>>>(S2, SS2, gn, bbn, 1.0f/NNODES, scale2, shift2);
    k_node2<<<391, 256, 0, stream>>>(h2, scale2, shift2, Wn2T, bn2, out);
}